// Round 7
// baseline (540.647 us; speedup 1.0000x reference)
//
#include <hip/hip_runtime.h>

typedef short short8 __attribute__((ext_vector_type(8)));
typedef short short4v __attribute__((ext_vector_type(4)));
typedef float f32x4 __attribute__((ext_vector_type(4)));

#define NT 550
#define NS 2209
#define NP 12
#define NBK 69
#define NSTILE 18
#define NGRP 9
#define GBK 8
#define GNRM 3.9894228040143f

typedef unsigned short bfu;

__device__ __forceinline__ bfu f2bf(float f) {
    unsigned int u = __float_as_uint(f);
    unsigned int r = (u + 0x7fffu + ((u >> 16) & 1u)) >> 16;
    return (bfu)r;
}

__device__ __forceinline__ float sigm(float x) {
    return __builtin_amdgcn_rcpf(1.0f + __expf(-x));
}

// ---------- weight conversion: fp32 -> transposed bf16 ----------
__global__ void k_prep(const float* __restrict__ W2, const float* __restrict__ W3,
                       const float* __restrict__ W4,
                       bfu* __restrict__ w2h, bfu* __restrict__ w3h, bfu* __restrict__ w4h) {
    int id = blockIdx.x * 256 + threadIdx.x;
    if (id < 8192) {                       // w2h[c][k]  c<128,k<64   from W2(64,128)
        int c = id >> 6, k = id & 63;
        w2h[id] = f2bf(W2[k * 128 + c]);
    } else if (id < 8192 + 32768) {        // w3h[c][k]  c<256,k<128  from W3(128,256)
        int j = id - 8192;
        int c = j >> 7, k = j & 127;
        w3h[j] = f2bf(W3[k * 256 + c]);
    } else {                               // w4h[s][k]  s<2304,k<256 from W4(256,2209)
        int j = id - 40960;
        int s = j >> 8, k = j & 255;
        w4h[j] = f2bf(s < NS ? W4[k * NS + s] : 0.0f);
    }
}

// ---------- bucketing ----------
__global__ void k_count(const float* __restrict__ el, int* __restrict__ counts) {
    int id = blockIdx.x * 256 + threadIdx.x;
    float z = el[id * 3 + 2];
    int bk = (int)(z * 0.125f);
    bk = bk < 0 ? 0 : (bk > NBK - 1 ? NBK - 1 : bk);
    atomicAdd(&counts[(id >> 13) * NBK + bk], 1);
}

__global__ void k_scan(const int* __restrict__ counts, int* __restrict__ offs) {
    __shared__ int a[512];
    int tid = threadIdx.x;
    int v = (tid < 4 * NBK) ? counts[tid] : 0;
    a[tid] = v;
    __syncthreads();
    for (int s = 1; s < 512; s <<= 1) {
        int t = (tid >= s) ? a[tid - s] : 0;
        __syncthreads();
        a[tid] += t;
        __syncthreads();
    }
    if (tid < 4 * NBK) offs[tid] = a[tid] - v;
}

__global__ void k_scatter(const float* __restrict__ el, const int* __restrict__ offs,
                          int* __restrict__ cur, int* __restrict__ idxl) {
    int id = blockIdx.x * 256 + threadIdx.x;
    float z = el[id * 3 + 2];
    int bk = (int)(z * 0.125f);
    bk = bk < 0 ? 0 : (bk > NBK - 1 ? NBK - 1 : bk);
    int key = (id >> 13) * NBK + bk;
    int pos = offs[key] + atomicAdd(&cur[key], 1);
    idxl[pos] = id;
}

// ---------- phase A: sipm MLP layers 1-3 -> s3h (linear, bf16) ----------
__global__ __launch_bounds__(256, 1) void k_mlp(
    const float* __restrict__ el,
    const float* __restrict__ Ws1, const float* __restrict__ bs1,
    const float* __restrict__ bs2, const float* __restrict__ bs3,
    const bfu* __restrict__ w2h, const bfu* __restrict__ w3h,
    bfu* __restrict__ s3h) {

    __shared__ __align__(16) bfu bufA[32768];
    __shared__ __align__(16) bfu w3t[32768];
    __shared__ float xyb[256];
    __shared__ float s1w[128];
    __shared__ float b1s[64], b2s[128], b3s[256];

    bfu* h1t = bufA;            // [n][64]
    bfu* w2t = bufA + 8192;     // [c][64]
    bfu* h2t = bufA + 16384;    // [n][128]

    const int tid = threadIdx.x;
    const int wv = tid >> 6, ln = tid & 63;
    const int e0 = blockIdx.x * 128;

    if (tid < 128) s1w[tid] = Ws1[tid];
    if (tid < 64) b1s[tid] = bs1[tid];
    if (tid < 128) b2s[tid] = bs2[tid];
    b3s[tid] = bs3[tid];

    if (tid < 128) {
        int e = e0 + tid;
        xyb[tid * 2] = el[e * 3]; xyb[tid * 2 + 1] = el[e * 3 + 1];
    }
    for (int i = 0; i < 4; ++i) {
        int cid = i * 256 + tid;
        int row = cid >> 3, c5 = cid & 7;
        short8 v = *(const short8*)(const void*)&w2h[row * 64 + c5 * 8];
        *(short8*)(void*)&w2t[row * 64 + ((c5 ^ (row & 7)) * 8)] = v;
    }
    for (int i = 0; i < 16; ++i) {
        int cid = i * 256 + tid;
        int row = cid >> 4, c5 = cid & 15;
        short8 v = *(const short8*)(const void*)&w3h[row * 128 + c5 * 8];
        *(short8*)(void*)&w3t[row * 128 + ((c5 ^ (row & 7)) * 8)] = v;
    }
    __syncthreads();

    // L1
    {
        int n = tid & 127;
        int j0 = (tid >> 7) * 32;
        float xx = xyb[n * 2], yy = xyb[n * 2 + 1];
        for (int jj = 0; jj < 32; ++jj) {
            int j = j0 + jj;
            float h = sigm(xx * s1w[j] + yy * s1w[64 + j] + b1s[j]);
            h1t[n * 64 + (((j >> 3) ^ (n & 7)) * 8) + (j & 7)] = f2bf(h);
        }
    }
    __syncthreads();

    // L2: (128x64)@(64x128)
    {
        const int mr = (wv >> 1) * 64;
        const int nc = (wv & 1) * 64;
        f32x4 acc[4][4];
        for (int m = 0; m < 4; ++m) for (int nf = 0; nf < 4; ++nf) acc[m][nf] = (f32x4){0.f, 0.f, 0.f, 0.f};
        for (int kk = 0; kk < 2; ++kk) {
            int kc = kk * 4 + (ln >> 4);
            short8 af[4], bf[4];
            for (int m = 0; m < 4; ++m) {
                int row = mr + 16 * m + (ln & 15);
                af[m] = *(const short8*)(const void*)&h1t[row * 64 + ((kc ^ (row & 7)) * 8)];
            }
            for (int nf = 0; nf < 4; ++nf) {
                int c = nc + 16 * nf + (ln & 15);
                bf[nf] = *(const short8*)(const void*)&w2t[c * 64 + ((kc ^ (c & 7)) * 8)];
            }
            for (int m = 0; m < 4; ++m)
                for (int nf = 0; nf < 4; ++nf)
                    acc[m][nf] = __builtin_amdgcn_mfma_f32_16x16x32_bf16(af[m], bf[nf], acc[m][nf], 0, 0, 0);
        }
        for (int m = 0; m < 4; ++m)
            for (int nf = 0; nf < 4; ++nf) {
                int c = nc + 16 * nf + (ln & 15);
                float bb = b2s[c];
                for (int r = 0; r < 4; ++r) {
                    int n = mr + 16 * m + (ln >> 4) * 4 + r;
                    float hh = sigm(acc[m][nf][r] + bb);
                    h2t[n * 128 + (((c >> 3) ^ (n & 7)) * 8) + (c & 7)] = f2bf(hh);
                }
            }
    }
    __syncthreads();

    // L3: (128x128)@(128x256)
    f32x4 acc3[4][8];
    const int mr3 = (wv >> 1) * 64;
    const int nc3 = (wv & 1) * 128;
    for (int m = 0; m < 4; ++m) for (int nf = 0; nf < 8; ++nf) acc3[m][nf] = (f32x4){0.f, 0.f, 0.f, 0.f};
    for (int kk = 0; kk < 4; ++kk) {
        int kc = kk * 4 + (ln >> 4);
        short8 af[4];
        for (int m = 0; m < 4; ++m) {
            int row = mr3 + 16 * m + (ln & 15);
            af[m] = *(const short8*)(const void*)&h2t[row * 128 + ((kc ^ (row & 7)) * 8)];
        }
        for (int nf = 0; nf < 8; ++nf) {
            int c = nc3 + 16 * nf + (ln & 15);
            short8 bf = *(const short8*)(const void*)&w3t[c * 128 + ((kc ^ (c & 7)) * 8)];
            for (int m = 0; m < 4; ++m)
                acc3[m][nf] = __builtin_amdgcn_mfma_f32_16x16x32_bf16(af[m], bf, acc3[m][nf], 0, 0, 0);
        }
    }
    __syncthreads();
    for (int m = 0; m < 4; ++m)
        for (int nf = 0; nf < 8; ++nf) {
            int c = nc3 + 16 * nf + (ln & 15);
            float bb = b3s[c];
            for (int r = 0; r < 4; ++r) {
                int n = mr3 + 16 * m + (ln >> 4) * 4 + r;
                float ss = sigm(acc3[m][nf][r] + bb);
                bufA[n * 256 + (((c >> 3) ^ (n & 7)) * 8) + (c & 7)] = f2bf(ss);
            }
        }
    __syncthreads();
    for (int i = 0; i < 16; ++i) {
        int cid = i * 256 + tid;
        int row = cid >> 5, c5 = cid & 31;
        short8 v = *(const short8*)(const void*)&bufA[row * 256 + ((c5 ^ (row & 7)) * 8)];
        *(short8*)(void*)&s3h[(size_t)(e0 + row) * 256 + c5 * 8] = v;
    }
}

// ---------- phase B: B-in-regs, 2x2 wave tiles, 66KB LDS (2 blocks/CU) ----------
__global__ __launch_bounds__(512, 4) void k_sipm(
    const float* __restrict__ el, const float* __restrict__ wt,
    const float* __restrict__ bs4, const float* __restrict__ sis,
    const float* __restrict__ Wp1, const float* __restrict__ bp1,
    const float* __restrict__ Wp2, const float* __restrict__ bp2,
    const float* __restrict__ psc,
    const bfu* __restrict__ s3h, const bfu* __restrict__ w4h,
    const int* __restrict__ idxl, const int* __restrict__ counts,
    const int* __restrict__ offs,
    float* __restrict__ outP, float* __restrict__ outS) {

    __shared__ __align__(16) bfu s3t[64 * 256];   // 32768, XOR swz
    __shared__ __align__(16) bfu rpt[128 * 64];   // 16384, XOR swz
    __shared__ __align__(16) bfu Et[16 * 64];     //  2048, XOR swz
    __shared__ __align__(16) bfu rpp[16 * 64];    //  2048, XOR swz
    __shared__ float accT[16 * 129];              //  8256 ring
    __shared__ float accP[64 * 12];               //  3072
    __shared__ float pwb[444];                    //  1776
    // total ~66.4 KB -> 2 blocks/CU

    const int tid = threadIdx.x;
    const int wv = tid >> 6, ln = tid & 63;
    const int bid = blockIdx.x;
    const int st  = bid % NSTILE;
    const int grp = (bid / NSTILE) % NGRP;
    const int b   = bid / (NSTILE * NGRP);
    const int bk0 = grp * GBK;
    const int bk1 = (bk0 + GBK < NBK) ? bk0 + GBK : NBK;
    const int T_lo = bk0 * 8 - 2;
    const int s0 = st * 128;
    const bool do_pmt = (st == 0);
    const int ws = (wv & 3) * 32;                 // GEMM1 s-group
    const int wn = (wv >> 2) * 32;                // GEMM1 n-group
    const int sg2 = 16 * wv + (ln & 15);          // GEMM2 s-col

    // ---- B operand in registers (once per block) ----
    short8 bfr[2][8];
    float bssr[2], si2r[2];
    for (int nf = 0; nf < 2; ++nf) {
        int scol = s0 + ws + 16 * nf + (ln & 15);
        for (int kk = 0; kk < 8; ++kk)
            bfr[nf][kk] = *(const short8*)(const void*)&w4h[(size_t)scol * 256 + (kk * 4 + (ln >> 4)) * 8];
        bssr[nf] = (scol < NS) ? bs4[scol] : 0.0f;
        float sc = (scol < NS) ? sis[scol] : 0.0f;
        si2r[nf] = sc * sc;
    }
    if (do_pmt) {
        if (tid < 444)
            pwb[tid] = (tid < 56) ? Wp1[tid] : (tid < 84) ? bp1[tid - 56] :
                       (tid < 420) ? Wp2[tid - 84] : (tid < 432) ? bp2[tid - 420] : psc[tid - 432];
        if (tid < 256) {   // zero rpp rows 12..15 once (never overwritten)
            int p = 12 + (tid >> 6), n = tid & 63;
            rpp[p * 64 + (((n >> 3) ^ (p & 7)) * 8) + (n & 7)] = 0;
        }
    }
    for (int i = tid; i < 16 * 129; i += 512) accT[i] = 0.f;
    for (int i = tid; i < 64 * 12; i += 512) accP[i] = 0.f;
    __syncthreads();

    int F = 0;
    for (int bk = (bk0 > 0 ? bk0 - 1 : 0); bk < bk1; ++bk) {
        const int key = b * NBK + bk;
        const int cnt = counts[key];               // block-uniform
        if (cnt == 0) continue;
        const int off = offs[key];
        const int db8 = (bk - bk0) * 8;

        // flush finalized ring rows [F, db8-2) — ordered: prev adds < bar3; next adds > bar2
        {
            int Fn = db8 - 2; Fn = Fn < 0 ? 0 : Fn;
            if (Fn > F) {
                for (int i = tid; i < (Fn - F) * 128; i += 512) {
                    int dr = i >> 7, s = i & 127;
                    int tl = F + dr;
                    float v = accT[(tl & 15) * 129 + s];
                    accT[(tl & 15) * 129 + s] = 0.f;
                    int tg = T_lo + tl, sg = s0 + s;
                    if (tg >= 0 && tg < NT && sg < NS)
                        outS[((size_t)b * NS + sg) * NT + tg] = v;
                }
                F = Fn;
            }
        }

        const int nch = (cnt + 63) >> 6;
        for (int c = 0; c < nch; ++c) {
            // ---- stage (direct; other block on CU hides latency) ----
            int liN = c * 64 + (tid & 63);
            int giN = off + liN; giN = giN > 32767 ? 32767 : giN;
            int eN = idxl[giN];
            float zN = el[eN * 3 + 2];
            float wN = (liN < cnt) ? wt[eN] : 0.0f;

            {   // s3 rows: 8 threads per row, 4 granules each
                int rowS = tid >> 3;
                int giS = off + c * 64 + rowS; giS = giS > 32767 ? 32767 : giS;
                int eS = idxl[giS];
                const bfu* srow = s3h + (size_t)eS * 256;
                short8 rg0 = *(const short8*)(const void*)&srow[((tid & 7) * 4 + 0) * 8];
                short8 rg1 = *(const short8*)(const void*)&srow[((tid & 7) * 4 + 1) * 8];
                short8 rg2 = *(const short8*)(const void*)&srow[((tid & 7) * 4 + 2) * 8];
                short8 rg3 = *(const short8*)(const void*)&srow[((tid & 7) * 4 + 3) * 8];
                int r3 = rowS & 7;
                bfu* drow = s3t + rowS * 256;
                *(short8*)(void*)&drow[((((tid & 7) * 4 + 0) ^ r3) * 8)] = rg0;
                *(short8*)(void*)&drow[((((tid & 7) * 4 + 1) ^ r3) * 8)] = rg1;
                *(short8*)(void*)&drow[((((tid & 7) * 4 + 2) ^ r3) * 8)] = rg2;
                *(short8*)(void*)&drow[((((tid & 7) * 4 + 3) ^ r3) * 8)] = rg3;
            }
            {   // gaussian tile Et[16][64]
                int n = tid & 63;
                for (int q = 0; q < 2; ++q) {
                    int j = (tid >> 6) * 2 + q;
                    int tg = bk * 8 - 4 + j;
                    int tl = tg - T_lo;
                    float d = (float)tg + 0.5f - zN;
                    bool ok = (tg >= 0) && (tg < NT) && (tl >= 0) && (tl < 64);
                    float g = ok ? wN * GNRM * __expf(-10.0f * d * d) : 0.0f;
                    Et[j * 64 + (((n >> 3) ^ (j & 7)) * 8) + (n & 7)] = f2bf(g);
                }
            }
            if (do_pmt && wv < 6) {                // pmt MLP, waves 0-5, 2 p's each
                float xx = el[eN * 3], yy = el[eN * 3 + 1];
                float hh[28];
                for (int j = 0; j < 28; ++j)
                    hh[j] = sigm(xx * pwb[j] + yy * pwb[28 + j] + pwb[56 + j]);
                for (int q = 0; q < 2; ++q) {
                    int p = wv * 2 + q;
                    float a = pwb[420 + p];
                    for (int j = 0; j < 28; ++j) a += hh[j] * pwb[84 + j * 12 + p];
                    float sc = pwb[432 + p];
                    int n = ln;
                    rpp[p * 64 + (((n >> 3) ^ (p & 7)) * 8) + (n & 7)] = f2bf(sigm(a) * sc * sc);
                }
            }
            __syncthreads();                       // bar1: stage visible

            // ---- GEMM1: (64n x 256k) @ (256k x 128s), wave tile 32n x 32s ----
            f32x4 acc[2][2];
            acc[0][0] = (f32x4){0.f,0.f,0.f,0.f}; acc[0][1] = (f32x4){0.f,0.f,0.f,0.f};
            acc[1][0] = (f32x4){0.f,0.f,0.f,0.f}; acc[1][1] = (f32x4){0.f,0.f,0.f,0.f};
            const int ar0 = wn + (ln & 15), ar1 = wn + 16 + (ln & 15);
#pragma unroll
            for (int kk = 0; kk < 8; ++kk) {
                int kc = kk * 4 + (ln >> 4);
                short8 a0 = *(const short8*)(const void*)&s3t[ar0 * 256 + ((kc ^ (ar0 & 7)) * 8)];
                short8 a1 = *(const short8*)(const void*)&s3t[ar1 * 256 + ((kc ^ (ar1 & 7)) * 8)];
                acc[0][0] = __builtin_amdgcn_mfma_f32_16x16x32_bf16(a0, bfr[0][kk], acc[0][0], 0, 0, 0);
                acc[0][1] = __builtin_amdgcn_mfma_f32_16x16x32_bf16(a0, bfr[1][kk], acc[0][1], 0, 0, 0);
                acc[1][0] = __builtin_amdgcn_mfma_f32_16x16x32_bf16(a1, bfr[0][kk], acc[1][0], 0, 0, 0);
                acc[1][1] = __builtin_amdgcn_mfma_f32_16x16x32_bf16(a1, bfr[1][kk], acc[1][1], 0, 0, 0);
            }
            for (int m = 0; m < 2; ++m)
                for (int nf = 0; nf < 2; ++nf) {
                    int scol = ws + 16 * nf + (ln & 15);
                    short4v pk;
                    for (int r = 0; r < 4; ++r)
                        pk[r] = (short)f2bf(si2r[nf] * sigm(acc[m][nf][r] + bssr[nf]));
                    int n0 = wn + 16 * m + (ln >> 4) * 4;
                    *(short4v*)(void*)&rpt[scol * 64 + (((n0 >> 3) ^ (scol & 7)) * 8) + (n0 & 7)] = pk;
                }
            __syncthreads();                       // bar2: rpt visible

            // ---- GEMM2: Et(16t x 64n) @ rpt(64n x 128s) -> ring ----
            {
                f32x4 a2 = (f32x4){0.f,0.f,0.f,0.f};
                f32x4 a2p = (f32x4){0.f,0.f,0.f,0.f};
                const int tr = ln & 15;
#pragma unroll
                for (int kk = 0; kk < 2; ++kk) {
                    int kc = kk * 4 + (ln >> 4);
                    short8 ea = *(const short8*)(const void*)&Et[tr * 64 + ((kc ^ (tr & 7)) * 8)];
                    short8 bb = *(const short8*)(const void*)&rpt[sg2 * 64 + ((kc ^ (sg2 & 7)) * 8)];
                    a2 = __builtin_amdgcn_mfma_f32_16x16x32_bf16(ea, bb, a2, 0, 0, 0);
                    if (do_pmt && wv == 0) {
                        short8 bp = *(const short8*)(const void*)&rpp[tr * 64 + ((kc ^ (tr & 7)) * 8)];
                        a2p = __builtin_amdgcn_mfma_f32_16x16x32_bf16(ea, bp, a2p, 0, 0, 0);
                    }
                }
                for (int r = 0; r < 4; ++r) {
                    int tl = db8 - 2 + (ln >> 4) * 4 + r;
                    if (tl >= 0 && tl < 64) accT[(tl & 15) * 129 + sg2] += a2[r];
                }
                if (do_pmt && wv == 0) {
                    int p = ln & 15;
                    if (p < 12)
                        for (int r = 0; r < 4; ++r) {
                            int tl = db8 - 2 + (ln >> 4) * 4 + r;
                            if (tl >= 0 && tl < 64) accP[tl * 12 + p] += a2p[r];
                        }
                }
            }
            __syncthreads();                       // bar3: GEMM2 reads done
        } // chunks
    } // buckets

    // final flush [F,64)
    for (int i = tid; i < (64 - F) * 128; i += 512) {
        int dr = i >> 7, s = i & 127;
        int tl = F + dr;
        int tg = T_lo + tl, sg = s0 + s;
        if (tg >= 0 && tg < NT && sg < NS)
            outS[((size_t)b * NS + sg) * NT + tg] = accT[(tl & 15) * 129 + s];
    }
    if (do_pmt) {
        for (int i = tid; i < 64 * 12; i += 512) {
            int tl = i / 12, p = i % 12;
            int tg = T_lo + tl;
            if (tg >= 0 && tg < NT)
                outP[((size_t)b * NP + p) * NT + tg] = accP[tl * 12 + p];
        }
    }
}

extern "C" void kernel_launch(void* const* d_in, const int* in_sizes, int n_in,
                              void* d_out, int out_size, void* d_ws, size_t ws_size,
                              hipStream_t stream) {
    const float* el  = (const float*)d_in[0];
    const float* wt  = (const float*)d_in[1];
    const float* Wp1 = (const float*)d_in[2];
    const float* bp1 = (const float*)d_in[3];
    const float* Wp2 = (const float*)d_in[4];
    const float* bp2 = (const float*)d_in[5];
    const float* psc = (const float*)d_in[6];
    const float* Ws1 = (const float*)d_in[7];
    const float* bs1 = (const float*)d_in[8];
    const float* Ws2 = (const float*)d_in[9];
    const float* bs2 = (const float*)d_in[10];
    const float* Ws3 = (const float*)d_in[11];
    const float* bs3 = (const float*)d_in[12];
    const float* Ws4 = (const float*)d_in[13];
    const float* bs4 = (const float*)d_in[14];
    const float* sis = (const float*)d_in[15];
    float* out = (float*)d_out;

    // workspace layout byte-identical to R2/R4/R5/R6 (proven within ws_size)
    char* ws = (char*)d_ws;
    bfu* w2h     = (bfu*)(ws);                    // 16384
    bfu* w3h     = (bfu*)(ws + 16384);            // 65536
    bfu* w4h     = (bfu*)(ws + 81920);            // 1179648
    bfu* s3h     = (bfu*)(ws + 1261568);          // 16777216
    int* counts  = (int*)(ws + 18038784);
    int* offs    = (int*)(ws + 18042880);
    int* cursors = (int*)(ws + 18046976);
    int* idxl    = (int*)(ws + 18051072);         // 131072 -> end 18182144

    hipMemsetAsync(counts, 0, 4096, stream);
    hipMemsetAsync(cursors, 0, 4096, stream);
    // d_out fully written by k_sipm exact-partition stores (proven R6)

    k_prep<<<2464, 256, 0, stream>>>(Ws2, Ws3, Ws4, w2h, w3h, w4h);
    k_count<<<128, 256, 0, stream>>>(el, counts);
    k_scan<<<1, 512, 0, stream>>>(counts, offs);
    k_scatter<<<128, 256, 0, stream>>>(el, offs, cursors, idxl);
    k_mlp<<<256, 256, 0, stream>>>(el, Ws1, bs1, bs2, bs3, w2h, w3h, s3h);
    k_sipm<<<4 * NGRP * NSTILE, 512, 0, stream>>>(el, wt, bs4, sis, Wp1, bp1, Wp2, bp2, psc,
                                                  s3h, w4h, idxl, counts, offs,
                                                  out, out + 4 * NP * NT);
}

// Round 8
// 508.446 us; speedup vs baseline: 1.0633x; 1.0633x over previous
//
#include <hip/hip_runtime.h>

typedef short short8 __attribute__((ext_vector_type(8)));
typedef short short4v __attribute__((ext_vector_type(4)));
typedef float f32x4 __attribute__((ext_vector_type(4)));

#define NT 550
#define NS 2209
#define NP 12
#define NBK 69
#define NSTILE 18
#define NGRP 9
#define GBK 8
#define GNRM 3.9894228040143f

typedef unsigned short bfu;

__device__ __forceinline__ bfu f2bf(float f) {
    unsigned int u = __float_as_uint(f);
    unsigned int r = (u + 0x7fffu + ((u >> 16) & 1u)) >> 16;
    return (bfu)r;
}

__device__ __forceinline__ float sigm(float x) {
    return __builtin_amdgcn_rcpf(1.0f + __expf(-x));
}

// ---------- weight conversion: fp32 -> transposed bf16 ----------
__global__ void k_prep(const float* __restrict__ W2, const float* __restrict__ W3,
                       const float* __restrict__ W4,
                       bfu* __restrict__ w2h, bfu* __restrict__ w3h, bfu* __restrict__ w4h) {
    int id = blockIdx.x * 256 + threadIdx.x;
    if (id < 8192) {                       // w2h[c][k]  c<128,k<64   from W2(64,128)
        int c = id >> 6, k = id & 63;
        w2h[id] = f2bf(W2[k * 128 + c]);
    } else if (id < 8192 + 32768) {        // w3h[c][k]  c<256,k<128  from W3(128,256)
        int j = id - 8192;
        int c = j >> 7, k = j & 127;
        w3h[j] = f2bf(W3[k * 256 + c]);
    } else {                               // w4h[s][k]  s<2304,k<256 from W4(256,2209)
        int j = id - 40960;
        int s = j >> 8, k = j & 255;
        w4h[j] = f2bf(s < NS ? W4[k * NS + s] : 0.0f);
    }
}

// ---------- bucketing ----------
__global__ void k_count(const float* __restrict__ el, int* __restrict__ counts) {
    int id = blockIdx.x * 256 + threadIdx.x;
    float z = el[id * 3 + 2];
    int bk = (int)(z * 0.125f);
    bk = bk < 0 ? 0 : (bk > NBK - 1 ? NBK - 1 : bk);
    atomicAdd(&counts[(id >> 13) * NBK + bk], 1);
}

__global__ void k_scan(const int* __restrict__ counts, int* __restrict__ offs) {
    __shared__ int a[512];
    int tid = threadIdx.x;
    int v = (tid < 4 * NBK) ? counts[tid] : 0;
    a[tid] = v;
    __syncthreads();
    for (int s = 1; s < 512; s <<= 1) {
        int t = (tid >= s) ? a[tid - s] : 0;
        __syncthreads();
        a[tid] += t;
        __syncthreads();
    }
    if (tid < 4 * NBK) offs[tid] = a[tid] - v;
}

__global__ void k_scatter(const float* __restrict__ el, const int* __restrict__ offs,
                          int* __restrict__ cur, int* __restrict__ idxl) {
    int id = blockIdx.x * 256 + threadIdx.x;
    float z = el[id * 3 + 2];
    int bk = (int)(z * 0.125f);
    bk = bk < 0 ? 0 : (bk > NBK - 1 ? NBK - 1 : bk);
    int key = (id >> 13) * NBK + bk;
    int pos = offs[key] + atomicAdd(&cur[key], 1);
    idxl[pos] = id;
}

// ---------- phase A: sipm MLP layers 1-3 -> s3h (linear, bf16) ----------
__global__ __launch_bounds__(256, 1) void k_mlp(
    const float* __restrict__ el,
    const float* __restrict__ Ws1, const float* __restrict__ bs1,
    const float* __restrict__ bs2, const float* __restrict__ bs3,
    const bfu* __restrict__ w2h, const bfu* __restrict__ w3h,
    bfu* __restrict__ s3h) {

    __shared__ __align__(16) bfu bufA[32768];
    __shared__ __align__(16) bfu w3t[32768];
    __shared__ float xyb[256];
    __shared__ float s1w[128];
    __shared__ float b1s[64], b2s[128], b3s[256];

    bfu* h1t = bufA;            // [n][64]
    bfu* w2t = bufA + 8192;     // [c][64]
    bfu* h2t = bufA + 16384;    // [n][128]

    const int tid = threadIdx.x;
    const int wv = tid >> 6, ln = tid & 63;
    const int e0 = blockIdx.x * 128;

    if (tid < 128) s1w[tid] = Ws1[tid];
    if (tid < 64) b1s[tid] = bs1[tid];
    if (tid < 128) b2s[tid] = bs2[tid];
    b3s[tid] = bs3[tid];

    if (tid < 128) {
        int e = e0 + tid;
        xyb[tid * 2] = el[e * 3]; xyb[tid * 2 + 1] = el[e * 3 + 1];
    }
    for (int i = 0; i < 4; ++i) {
        int cid = i * 256 + tid;
        int row = cid >> 3, c5 = cid & 7;
        short8 v = *(const short8*)(const void*)&w2h[row * 64 + c5 * 8];
        *(short8*)(void*)&w2t[row * 64 + ((c5 ^ (row & 7)) * 8)] = v;
    }
    for (int i = 0; i < 16; ++i) {
        int cid = i * 256 + tid;
        int row = cid >> 4, c5 = cid & 15;
        short8 v = *(const short8*)(const void*)&w3h[row * 128 + c5 * 8];
        *(short8*)(void*)&w3t[row * 128 + ((c5 ^ (row & 7)) * 8)] = v;
    }
    __syncthreads();

    // L1
    {
        int n = tid & 127;
        int j0 = (tid >> 7) * 32;
        float xx = xyb[n * 2], yy = xyb[n * 2 + 1];
        for (int jj = 0; jj < 32; ++jj) {
            int j = j0 + jj;
            float h = sigm(xx * s1w[j] + yy * s1w[64 + j] + b1s[j]);
            h1t[n * 64 + (((j >> 3) ^ (n & 7)) * 8) + (j & 7)] = f2bf(h);
        }
    }
    __syncthreads();

    // L2: (128x64)@(64x128)
    {
        const int mr = (wv >> 1) * 64;
        const int nc = (wv & 1) * 64;
        f32x4 acc[4][4];
        for (int m = 0; m < 4; ++m) for (int nf = 0; nf < 4; ++nf) acc[m][nf] = (f32x4){0.f, 0.f, 0.f, 0.f};
        for (int kk = 0; kk < 2; ++kk) {
            int kc = kk * 4 + (ln >> 4);
            short8 af[4], bf[4];
            for (int m = 0; m < 4; ++m) {
                int row = mr + 16 * m + (ln & 15);
                af[m] = *(const short8*)(const void*)&h1t[row * 64 + ((kc ^ (row & 7)) * 8)];
            }
            for (int nf = 0; nf < 4; ++nf) {
                int c = nc + 16 * nf + (ln & 15);
                bf[nf] = *(const short8*)(const void*)&w2t[c * 64 + ((kc ^ (c & 7)) * 8)];
            }
            for (int m = 0; m < 4; ++m)
                for (int nf = 0; nf < 4; ++nf)
                    acc[m][nf] = __builtin_amdgcn_mfma_f32_16x16x32_bf16(af[m], bf[nf], acc[m][nf], 0, 0, 0);
        }
        for (int m = 0; m < 4; ++m)
            for (int nf = 0; nf < 4; ++nf) {
                int c = nc + 16 * nf + (ln & 15);
                float bb = b2s[c];
                for (int r = 0; r < 4; ++r) {
                    int n = mr + 16 * m + (ln >> 4) * 4 + r;
                    float hh = sigm(acc[m][nf][r] + bb);
                    h2t[n * 128 + (((c >> 3) ^ (n & 7)) * 8) + (c & 7)] = f2bf(hh);
                }
            }
    }
    __syncthreads();

    // L3: (128x128)@(128x256)
    f32x4 acc3[4][8];
    const int mr3 = (wv >> 1) * 64;
    const int nc3 = (wv & 1) * 128;
    for (int m = 0; m < 4; ++m) for (int nf = 0; nf < 8; ++nf) acc3[m][nf] = (f32x4){0.f, 0.f, 0.f, 0.f};
    for (int kk = 0; kk < 4; ++kk) {
        int kc = kk * 4 + (ln >> 4);
        short8 af[4];
        for (int m = 0; m < 4; ++m) {
            int row = mr3 + 16 * m + (ln & 15);
            af[m] = *(const short8*)(const void*)&h2t[row * 128 + ((kc ^ (row & 7)) * 8)];
        }
        for (int nf = 0; nf < 8; ++nf) {
            int c = nc3 + 16 * nf + (ln & 15);
            short8 bf = *(const short8*)(const void*)&w3t[c * 128 + ((kc ^ (c & 7)) * 8)];
            for (int m = 0; m < 4; ++m)
                acc3[m][nf] = __builtin_amdgcn_mfma_f32_16x16x32_bf16(af[m], bf, acc3[m][nf], 0, 0, 0);
        }
    }
    __syncthreads();
    for (int m = 0; m < 4; ++m)
        for (int nf = 0; nf < 8; ++nf) {
            int c = nc3 + 16 * nf + (ln & 15);
            float bb = b3s[c];
            for (int r = 0; r < 4; ++r) {
                int n = mr3 + 16 * m + (ln >> 4) * 4 + r;
                float ss = sigm(acc3[m][nf][r] + bb);
                bufA[n * 256 + (((c >> 3) ^ (n & 7)) * 8) + (c & 7)] = f2bf(ss);
            }
        }
    __syncthreads();
    for (int i = 0; i < 16; ++i) {
        int cid = i * 256 + tid;
        int row = cid >> 5, c5 = cid & 31;
        short8 v = *(const short8*)(const void*)&bufA[row * 256 + ((c5 ^ (row & 7)) * 8)];
        *(short8*)(void*)&s3h[(size_t)(e0 + row) * 256 + c5 * 8] = v;
    }
}

// ---------- phase B: B-in-regs (statically indexed), 2x2 wave tiles, 66KB LDS ----------
__global__ __launch_bounds__(512, 4) void k_sipm(
    const float* __restrict__ el, const float* __restrict__ wt,
    const float* __restrict__ bs4, const float* __restrict__ sis,
    const float* __restrict__ Wp1, const float* __restrict__ bp1,
    const float* __restrict__ Wp2, const float* __restrict__ bp2,
    const float* __restrict__ psc,
    const bfu* __restrict__ s3h, const bfu* __restrict__ w4h,
    const int* __restrict__ idxl, const int* __restrict__ counts,
    const int* __restrict__ offs,
    float* __restrict__ outP, float* __restrict__ outS) {

    __shared__ __align__(16) bfu s3t[64 * 256];   // 32768, XOR swz
    __shared__ __align__(16) bfu rpt[128 * 64];   // 16384, XOR swz
    __shared__ __align__(16) bfu Et[16 * 64];     //  2048, XOR swz
    __shared__ __align__(16) bfu rpp[16 * 64];    //  2048, XOR swz
    __shared__ float accT[16 * 129];              //  8256 ring
    __shared__ float accP[64 * 12];               //  3072
    __shared__ float pwb[444];                    //  1776
    // total ~66.4 KB -> 2 blocks/CU

    const int tid = threadIdx.x;
    const int wv = tid >> 6, ln = tid & 63;
    const int bid = blockIdx.x;
    const int st  = bid % NSTILE;
    const int grp = (bid / NSTILE) % NGRP;
    const int b   = bid / (NSTILE * NGRP);
    const int bk0 = grp * GBK;
    const int bk1 = (bk0 + GBK < NBK) ? bk0 + GBK : NBK;
    const int T_lo = bk0 * 8 - 2;
    const int s0 = st * 128;
    const bool do_pmt = (st == 0);
    const int ws = (wv & 3) * 32;                 // GEMM1 s-group
    const int wn = (wv >> 2) * 32;                // GEMM1 n-group
    const int sg2 = 16 * wv + (ln & 15);          // GEMM2 s-col

    // ---- B operand in registers (once per block); FULLY UNROLLED (rule #20) ----
    short8 bfr[2][8];
    float bssr[2], si2r[2];
#pragma unroll
    for (int nf = 0; nf < 2; ++nf) {
        int scol = s0 + ws + 16 * nf + (ln & 15);
        const bfu* wp = &w4h[(size_t)scol * 256 + (ln >> 4) * 8];
#pragma unroll
        for (int kk = 0; kk < 8; ++kk)
            bfr[nf][kk] = *(const short8*)(const void*)&wp[kk * 32];
        bssr[nf] = (scol < NS) ? bs4[scol] : 0.0f;
        float sc = (scol < NS) ? sis[scol] : 0.0f;
        si2r[nf] = sc * sc;
    }
    if (do_pmt) {
        if (tid < 444)
            pwb[tid] = (tid < 56) ? Wp1[tid] : (tid < 84) ? bp1[tid - 56] :
                       (tid < 420) ? Wp2[tid - 84] : (tid < 432) ? bp2[tid - 420] : psc[tid - 432];
        if (tid < 256) {   // zero rpp rows 12..15 once (never overwritten)
            int p = 12 + (tid >> 6), n = tid & 63;
            rpp[p * 64 + (((n >> 3) ^ (p & 7)) * 8) + (n & 7)] = 0;
        }
    }
    for (int i = tid; i < 16 * 129; i += 512) accT[i] = 0.f;
    for (int i = tid; i < 64 * 12; i += 512) accP[i] = 0.f;
    __syncthreads();

    int F = 0;
    for (int bk = (bk0 > 0 ? bk0 - 1 : 0); bk < bk1; ++bk) {
        const int key = b * NBK + bk;
        const int cnt = counts[key];               // block-uniform
        if (cnt == 0) continue;
        const int off = offs[key];
        const int db8 = (bk - bk0) * 8;

        // flush finalized ring rows [F, db8-2)
        {
            int Fn = db8 - 2; Fn = Fn < 0 ? 0 : Fn;
            if (Fn > F) {
                for (int i = tid; i < (Fn - F) * 128; i += 512) {
                    int dr = i >> 7, s = i & 127;
                    int tl = F + dr;
                    float v = accT[(tl & 15) * 129 + s];
                    accT[(tl & 15) * 129 + s] = 0.f;
                    int tg = T_lo + tl, sg = s0 + s;
                    if (tg >= 0 && tg < NT && sg < NS)
                        outS[((size_t)b * NS + sg) * NT + tg] = v;
                }
                F = Fn;
            }
        }

        const int nch = (cnt + 63) >> 6;
        for (int c = 0; c < nch; ++c) {
            // ---- stage (direct; co-resident block hides latency) ----
            int liN = c * 64 + (tid & 63);
            int giN = off + liN; giN = giN > 32767 ? 32767 : giN;
            int eN = idxl[giN];
            float zN = el[eN * 3 + 2];
            float wN = (liN < cnt) ? wt[eN] : 0.0f;

            {   // s3 rows: 8 threads per row, 4 granules each (named regs, static)
                int rowS = tid >> 3;
                int giS = off + c * 64 + rowS; giS = giS > 32767 ? 32767 : giS;
                int eS = idxl[giS];
                const bfu* srow = s3h + (size_t)eS * 256;
                short8 rg0 = *(const short8*)(const void*)&srow[((tid & 7) * 4 + 0) * 8];
                short8 rg1 = *(const short8*)(const void*)&srow[((tid & 7) * 4 + 1) * 8];
                short8 rg2 = *(const short8*)(const void*)&srow[((tid & 7) * 4 + 2) * 8];
                short8 rg3 = *(const short8*)(const void*)&srow[((tid & 7) * 4 + 3) * 8];
                int r3 = rowS & 7;
                bfu* drow = s3t + rowS * 256;
                *(short8*)(void*)&drow[((((tid & 7) * 4 + 0) ^ r3) * 8)] = rg0;
                *(short8*)(void*)&drow[((((tid & 7) * 4 + 1) ^ r3) * 8)] = rg1;
                *(short8*)(void*)&drow[((((tid & 7) * 4 + 2) ^ r3) * 8)] = rg2;
                *(short8*)(void*)&drow[((((tid & 7) * 4 + 3) ^ r3) * 8)] = rg3;
            }
            {   // gaussian tile Et[16][64]
                int n = tid & 63;
#pragma unroll
                for (int q = 0; q < 2; ++q) {
                    int j = (tid >> 6) * 2 + q;
                    int tg = bk * 8 - 4 + j;
                    int tl = tg - T_lo;
                    float d = (float)tg + 0.5f - zN;
                    bool ok = (tg >= 0) && (tg < NT) && (tl >= 0) && (tl < 64);
                    float g = ok ? wN * GNRM * __expf(-10.0f * d * d) : 0.0f;
                    Et[j * 64 + (((n >> 3) ^ (j & 7)) * 8) + (n & 7)] = f2bf(g);
                }
            }
            if (do_pmt && wv < 6) {                // pmt MLP, waves 0-5, 2 p's each
                float xx = el[eN * 3], yy = el[eN * 3 + 1];
                float hh[28];
#pragma unroll
                for (int j = 0; j < 28; ++j)
                    hh[j] = sigm(xx * pwb[j] + yy * pwb[28 + j] + pwb[56 + j]);
#pragma unroll
                for (int q = 0; q < 2; ++q) {
                    int p = wv * 2 + q;
                    float a = pwb[420 + p];
#pragma unroll
                    for (int j = 0; j < 28; ++j) a += hh[j] * pwb[84 + j * 12 + p];
                    float sc = pwb[432 + p];
                    int n = ln;
                    rpp[p * 64 + (((n >> 3) ^ (p & 7)) * 8) + (n & 7)] = f2bf(sigm(a) * sc * sc);
                }
            }
            __syncthreads();                       // bar1: stage visible

            // ---- GEMM1: (64n x 256k) @ (256k x 128s), wave tile 32n x 32s ----
            f32x4 acc00 = (f32x4){0.f,0.f,0.f,0.f};
            f32x4 acc01 = (f32x4){0.f,0.f,0.f,0.f};
            f32x4 acc10 = (f32x4){0.f,0.f,0.f,0.f};
            f32x4 acc11 = (f32x4){0.f,0.f,0.f,0.f};
            const int ar0 = wn + (ln & 15), ar1 = wn + 16 + (ln & 15);
#pragma unroll
            for (int kk = 0; kk < 8; ++kk) {
                int kc = kk * 4 + (ln >> 4);
                short8 a0 = *(const short8*)(const void*)&s3t[ar0 * 256 + ((kc ^ (ar0 & 7)) * 8)];
                short8 a1 = *(const short8*)(const void*)&s3t[ar1 * 256 + ((kc ^ (ar1 & 7)) * 8)];
                acc00 = __builtin_amdgcn_mfma_f32_16x16x32_bf16(a0, bfr[0][kk], acc00, 0, 0, 0);
                acc01 = __builtin_amdgcn_mfma_f32_16x16x32_bf16(a0, bfr[1][kk], acc01, 0, 0, 0);
                acc10 = __builtin_amdgcn_mfma_f32_16x16x32_bf16(a1, bfr[0][kk], acc10, 0, 0, 0);
                acc11 = __builtin_amdgcn_mfma_f32_16x16x32_bf16(a1, bfr[1][kk], acc11, 0, 0, 0);
            }
            {   // epilogue, fully static
                int sc0 = ws + (ln & 15);
                int sc1 = ws + 16 + (ln & 15);
                int n0a = wn + (ln >> 4) * 4;
                int n0b = wn + 16 + (ln >> 4) * 4;
                short4v pk;
#pragma unroll
                for (int r = 0; r < 4; ++r) pk[r] = (short)f2bf(si2r[0] * sigm(acc00[r] + bssr[0]));
                *(short4v*)(void*)&rpt[sc0 * 64 + (((n0a >> 3) ^ (sc0 & 7)) * 8) + (n0a & 7)] = pk;
#pragma unroll
                for (int r = 0; r < 4; ++r) pk[r] = (short)f2bf(si2r[1] * sigm(acc01[r] + bssr[1]));
                *(short4v*)(void*)&rpt[sc1 * 64 + (((n0a >> 3) ^ (sc1 & 7)) * 8) + (n0a & 7)] = pk;
#pragma unroll
                for (int r = 0; r < 4; ++r) pk[r] = (short)f2bf(si2r[0] * sigm(acc10[r] + bssr[0]));
                *(short4v*)(void*)&rpt[sc0 * 64 + (((n0b >> 3) ^ (sc0 & 7)) * 8) + (n0b & 7)] = pk;
#pragma unroll
                for (int r = 0; r < 4; ++r) pk[r] = (short)f2bf(si2r[1] * sigm(acc11[r] + bssr[1]));
                *(short4v*)(void*)&rpt[sc1 * 64 + (((n0b >> 3) ^ (sc1 & 7)) * 8) + (n0b & 7)] = pk;
            }
            __syncthreads();                       // bar2: rpt visible

            // ---- GEMM2: Et(16t x 64n) @ rpt(64n x 128s) -> ring ----
            {
                f32x4 a2 = (f32x4){0.f,0.f,0.f,0.f};
                f32x4 a2p = (f32x4){0.f,0.f,0.f,0.f};
                const int tr = ln & 15;
#pragma unroll
                for (int kk = 0; kk < 2; ++kk) {
                    int kc = kk * 4 + (ln >> 4);
                    short8 ea = *(const short8*)(const void*)&Et[tr * 64 + ((kc ^ (tr & 7)) * 8)];
                    short8 bb = *(const short8*)(const void*)&rpt[sg2 * 64 + ((kc ^ (sg2 & 7)) * 8)];
                    a2 = __builtin_amdgcn_mfma_f32_16x16x32_bf16(ea, bb, a2, 0, 0, 0);
                    if (do_pmt && wv == 0) {
                        short8 bp = *(const short8*)(const void*)&rpp[tr * 64 + ((kc ^ (tr & 7)) * 8)];
                        a2p = __builtin_amdgcn_mfma_f32_16x16x32_bf16(ea, bp, a2p, 0, 0, 0);
                    }
                }
#pragma unroll
                for (int r = 0; r < 4; ++r) {
                    int tl = db8 - 2 + (ln >> 4) * 4 + r;
                    if (tl >= 0 && tl < 64) accT[(tl & 15) * 129 + sg2] += a2[r];
                }
                if (do_pmt && wv == 0) {
                    int p = ln & 15;
                    if (p < 12) {
#pragma unroll
                        for (int r = 0; r < 4; ++r) {
                            int tl = db8 - 2 + (ln >> 4) * 4 + r;
                            if (tl >= 0 && tl < 64) accP[tl * 12 + p] += a2p[r];
                        }
                    }
                }
            }
            __syncthreads();                       // bar3: GEMM2 reads done
        } // chunks
    } // buckets

    // final flush [F,64)
    for (int i = tid; i < (64 - F) * 128; i += 512) {
        int dr = i >> 7, s = i & 127;
        int tl = F + dr;
        int tg = T_lo + tl, sg = s0 + s;
        if (tg >= 0 && tg < NT && sg < NS)
            outS[((size_t)b * NS + sg) * NT + tg] = accT[(tl & 15) * 129 + s];
    }
    if (do_pmt) {
        for (int i = tid; i < 64 * 12; i += 512) {
            int tl = i / 12, p = i % 12;
            int tg = T_lo + tl;
            if (tg >= 0 && tg < NT)
                outP[((size_t)b * NP + p) * NT + tg] = accP[tl * 12 + p];
        }
    }
}

extern "C" void kernel_launch(void* const* d_in, const int* in_sizes, int n_in,
                              void* d_out, int out_size, void* d_ws, size_t ws_size,
                              hipStream_t stream) {
    const float* el  = (const float*)d_in[0];
    const float* wt  = (const float*)d_in[1];
    const float* Wp1 = (const float*)d_in[2];
    const float* bp1 = (const float*)d_in[3];
    const float* Wp2 = (const float*)d_in[4];
    const float* bp2 = (const float*)d_in[5];
    const float* psc = (const float*)d_in[6];
    const float* Ws1 = (const float*)d_in[7];
    const float* bs1 = (const float*)d_in[8];
    const float* Ws2 = (const float*)d_in[9];
    const float* bs2 = (const float*)d_in[10];
    const float* Ws3 = (const float*)d_in[11];
    const float* bs3 = (const float*)d_in[12];
    const float* Ws4 = (const float*)d_in[13];
    const float* bs4 = (const float*)d_in[14];
    const float* sis = (const float*)d_in[15];
    float* out = (float*)d_out;

    // workspace layout byte-identical to R2/R4/R5/R6/R7 (proven within ws_size)
    char* ws = (char*)d_ws;
    bfu* w2h     = (bfu*)(ws);                    // 16384
    bfu* w3h     = (bfu*)(ws + 16384);            // 65536
    bfu* w4h     = (bfu*)(ws + 81920);            // 1179648
    bfu* s3h     = (bfu*)(ws + 1261568);          // 16777216
    int* counts  = (int*)(ws + 18038784);
    int* offs    = (int*)(ws + 18042880);
    int* cursors = (int*)(ws + 18046976);
    int* idxl    = (int*)(ws + 18051072);         // 131072 -> end 18182144

    hipMemsetAsync(counts, 0, 4096, stream);
    hipMemsetAsync(cursors, 0, 4096, stream);
    // d_out fully written by k_sipm exact-partition stores (proven R6/R7)

    k_prep<<<2464, 256, 0, stream>>>(Ws2, Ws3, Ws4, w2h, w3h, w4h);
    k_count<<<128, 256, 0, stream>>>(el, counts);
    k_scan<<<1, 512, 0, stream>>>(counts, offs);
    k_scatter<<<128, 256, 0, stream>>>(el, offs, cursors, idxl);
    k_mlp<<<256, 256, 0, stream>>>(el, Ws1, bs1, bs2, bs3, w2h, w3h, s3h);
    k_sipm<<<4 * NGRP * NSTILE, 512, 0, stream>>>(el, wt, bs4, sis, Wp1, bp1, Wp2, bp2, psc,
                                                  s3h, w4h, idxl, counts, offs,
                                                  out, out + 4 * NP * NT);
}

// Round 9
// 287.886 us; speedup vs baseline: 1.8780x; 1.7661x over previous
//
#include <hip/hip_runtime.h>

typedef short short8 __attribute__((ext_vector_type(8)));
typedef short short4v __attribute__((ext_vector_type(4)));
typedef float f32x4 __attribute__((ext_vector_type(4)));

#define NT 550
#define NS 2209
#define NP 12
#define NBK 69
#define NSTILE 18
#define NGRP 9
#define GBK 8
#define GNRM 3.9894228040143f

typedef unsigned short bfu;

__device__ __forceinline__ bfu f2bf(float f) {
    unsigned int u = __float_as_uint(f);
    unsigned int r = (u + 0x7fffu + ((u >> 16) & 1u)) >> 16;
    return (bfu)r;
}

__device__ __forceinline__ float sigm(float x) {
    return __builtin_amdgcn_rcpf(1.0f + __expf(-x));
}

// ---------- weight conversion: fp32 -> transposed bf16 ----------
__global__ void k_prep(const float* __restrict__ W2, const float* __restrict__ W3,
                       const float* __restrict__ W4,
                       bfu* __restrict__ w2h, bfu* __restrict__ w3h, bfu* __restrict__ w4h) {
    int id = blockIdx.x * 256 + threadIdx.x;
    if (id < 8192) {                       // w2h[c][k]  c<128,k<64   from W2(64,128)
        int c = id >> 6, k = id & 63;
        w2h[id] = f2bf(W2[k * 128 + c]);
    } else if (id < 8192 + 32768) {        // w3h[c][k]  c<256,k<128  from W3(128,256)
        int j = id - 8192;
        int c = j >> 7, k = j & 127;
        w3h[j] = f2bf(W3[k * 256 + c]);
    } else {                               // w4h[s][k]  s<2304,k<256 from W4(256,2209)
        int j = id - 40960;
        int s = j >> 8, k = j & 255;
        w4h[j] = f2bf(s < NS ? W4[k * NS + s] : 0.0f);
    }
}

// ---------- bucketing ----------
__global__ void k_count(const float* __restrict__ el, int* __restrict__ counts) {
    int id = blockIdx.x * 256 + threadIdx.x;
    float z = el[id * 3 + 2];
    int bk = (int)(z * 0.125f);
    bk = bk < 0 ? 0 : (bk > NBK - 1 ? NBK - 1 : bk);
    atomicAdd(&counts[(id >> 13) * NBK + bk], 1);
}

__global__ void k_scan(const int* __restrict__ counts, int* __restrict__ offs) {
    __shared__ int a[512];
    int tid = threadIdx.x;
    int v = (tid < 4 * NBK) ? counts[tid] : 0;
    a[tid] = v;
    __syncthreads();
    for (int s = 1; s < 512; s <<= 1) {
        int t = (tid >= s) ? a[tid - s] : 0;
        __syncthreads();
        a[tid] += t;
        __syncthreads();
    }
    if (tid < 4 * NBK) offs[tid] = a[tid] - v;
}

__global__ void k_scatter(const float* __restrict__ el, const int* __restrict__ offs,
                          int* __restrict__ cur, int* __restrict__ idxl) {
    int id = blockIdx.x * 256 + threadIdx.x;
    float z = el[id * 3 + 2];
    int bk = (int)(z * 0.125f);
    bk = bk < 0 ? 0 : (bk > NBK - 1 ? NBK - 1 : bk);
    int key = (id >> 13) * NBK + bk;
    int pos = offs[key] + atomicAdd(&cur[key], 1);
    idxl[pos] = id;
}

// ---------- phase A: sipm MLP layers 1-3 -> s3h (linear, bf16) ----------
__global__ __launch_bounds__(256, 1) void k_mlp(
    const float* __restrict__ el,
    const float* __restrict__ Ws1, const float* __restrict__ bs1,
    const float* __restrict__ bs2, const float* __restrict__ bs3,
    const bfu* __restrict__ w2h, const bfu* __restrict__ w3h,
    bfu* __restrict__ s3h) {

    __shared__ __align__(16) bfu bufA[32768];
    __shared__ __align__(16) bfu w3t[32768];
    __shared__ float xyb[256];
    __shared__ float s1w[128];
    __shared__ float b1s[64], b2s[128], b3s[256];

    bfu* h1t = bufA;            // [n][64]
    bfu* w2t = bufA + 8192;     // [c][64]
    bfu* h2t = bufA + 16384;    // [n][128]

    const int tid = threadIdx.x;
    const int wv = tid >> 6, ln = tid & 63;
    const int e0 = blockIdx.x * 128;

    if (tid < 128) s1w[tid] = Ws1[tid];
    if (tid < 64) b1s[tid] = bs1[tid];
    if (tid < 128) b2s[tid] = bs2[tid];
    b3s[tid] = bs3[tid];

    if (tid < 128) {
        int e = e0 + tid;
        xyb[tid * 2] = el[e * 3]; xyb[tid * 2 + 1] = el[e * 3 + 1];
    }
    for (int i = 0; i < 4; ++i) {
        int cid = i * 256 + tid;
        int row = cid >> 3, c5 = cid & 7;
        short8 v = *(const short8*)(const void*)&w2h[row * 64 + c5 * 8];
        *(short8*)(void*)&w2t[row * 64 + ((c5 ^ (row & 7)) * 8)] = v;
    }
    for (int i = 0; i < 16; ++i) {
        int cid = i * 256 + tid;
        int row = cid >> 4, c5 = cid & 15;
        short8 v = *(const short8*)(const void*)&w3h[row * 128 + c5 * 8];
        *(short8*)(void*)&w3t[row * 128 + ((c5 ^ (row & 7)) * 8)] = v;
    }
    __syncthreads();

    // L1
    {
        int n = tid & 127;
        int j0 = (tid >> 7) * 32;
        float xx = xyb[n * 2], yy = xyb[n * 2 + 1];
        for (int jj = 0; jj < 32; ++jj) {
            int j = j0 + jj;
            float h = sigm(xx * s1w[j] + yy * s1w[64 + j] + b1s[j]);
            h1t[n * 64 + (((j >> 3) ^ (n & 7)) * 8) + (j & 7)] = f2bf(h);
        }
    }
    __syncthreads();

    // L2: (128x64)@(64x128)
    {
        const int mr = (wv >> 1) * 64;
        const int nc = (wv & 1) * 64;
        f32x4 acc[4][4];
        for (int m = 0; m < 4; ++m) for (int nf = 0; nf < 4; ++nf) acc[m][nf] = (f32x4){0.f, 0.f, 0.f, 0.f};
        for (int kk = 0; kk < 2; ++kk) {
            int kc = kk * 4 + (ln >> 4);
            short8 af[4], bf[4];
            for (int m = 0; m < 4; ++m) {
                int row = mr + 16 * m + (ln & 15);
                af[m] = *(const short8*)(const void*)&h1t[row * 64 + ((kc ^ (row & 7)) * 8)];
            }
            for (int nf = 0; nf < 4; ++nf) {
                int c = nc + 16 * nf + (ln & 15);
                bf[nf] = *(const short8*)(const void*)&w2t[c * 64 + ((kc ^ (c & 7)) * 8)];
            }
            for (int m = 0; m < 4; ++m)
                for (int nf = 0; nf < 4; ++nf)
                    acc[m][nf] = __builtin_amdgcn_mfma_f32_16x16x32_bf16(af[m], bf[nf], acc[m][nf], 0, 0, 0);
        }
        for (int m = 0; m < 4; ++m)
            for (int nf = 0; nf < 4; ++nf) {
                int c = nc + 16 * nf + (ln & 15);
                float bb = b2s[c];
                for (int r = 0; r < 4; ++r) {
                    int n = mr + 16 * m + (ln >> 4) * 4 + r;
                    float hh = sigm(acc[m][nf][r] + bb);
                    h2t[n * 128 + (((c >> 3) ^ (n & 7)) * 8) + (c & 7)] = f2bf(hh);
                }
            }
    }
    __syncthreads();

    // L3: (128x128)@(128x256)
    f32x4 acc3[4][8];
    const int mr3 = (wv >> 1) * 64;
    const int nc3 = (wv & 1) * 128;
    for (int m = 0; m < 4; ++m) for (int nf = 0; nf < 8; ++nf) acc3[m][nf] = (f32x4){0.f, 0.f, 0.f, 0.f};
    for (int kk = 0; kk < 4; ++kk) {
        int kc = kk * 4 + (ln >> 4);
        short8 af[4];
        for (int m = 0; m < 4; ++m) {
            int row = mr3 + 16 * m + (ln & 15);
            af[m] = *(const short8*)(const void*)&h2t[row * 128 + ((kc ^ (row & 7)) * 8)];
        }
        for (int nf = 0; nf < 8; ++nf) {
            int c = nc3 + 16 * nf + (ln & 15);
            short8 bf = *(const short8*)(const void*)&w3t[c * 128 + ((kc ^ (c & 7)) * 8)];
            for (int m = 0; m < 4; ++m)
                acc3[m][nf] = __builtin_amdgcn_mfma_f32_16x16x32_bf16(af[m], bf, acc3[m][nf], 0, 0, 0);
        }
    }
    __syncthreads();
    for (int m = 0; m < 4; ++m)
        for (int nf = 0; nf < 8; ++nf) {
            int c = nc3 + 16 * nf + (ln & 15);
            float bb = b3s[c];
            for (int r = 0; r < 4; ++r) {
                int n = mr3 + 16 * m + (ln >> 4) * 4 + r;
                float ss = sigm(acc3[m][nf][r] + bb);
                bufA[n * 256 + (((c >> 3) ^ (n & 7)) * 8) + (c & 7)] = f2bf(ss);
            }
        }
    __syncthreads();
    for (int i = 0; i < 16; ++i) {
        int cid = i * 256 + tid;
        int row = cid >> 5, c5 = cid & 31;
        short8 v = *(const short8*)(const void*)&bufA[row * 256 + ((c5 ^ (row & 7)) * 8)];
        *(short8*)(void*)&s3h[(size_t)(e0 + row) * 256 + c5 * 8] = v;
    }
}

// ---------- phase B: B-in-regs, 2x2 wave tiles, 66KB LDS, 128-VGPR cap ----------
__global__ __launch_bounds__(512, 2) void k_sipm(
    const float* __restrict__ el, const float* __restrict__ wt,
    const float* __restrict__ bs4, const float* __restrict__ sis,
    const float* __restrict__ Wp1, const float* __restrict__ bp1,
    const float* __restrict__ Wp2, const float* __restrict__ bp2,
    const float* __restrict__ psc,
    const bfu* __restrict__ s3h, const bfu* __restrict__ w4h,
    const int* __restrict__ idxl, const int* __restrict__ counts,
    const int* __restrict__ offs,
    float* __restrict__ outP, float* __restrict__ outS) {

    __shared__ __align__(16) bfu s3t[64 * 256];   // 32768, XOR swz
    __shared__ __align__(16) bfu rpt[128 * 64];   // 16384, XOR swz
    __shared__ __align__(16) bfu Et[16 * 64];     //  2048, XOR swz
    __shared__ __align__(16) bfu rpp[16 * 64];    //  2048, XOR swz
    __shared__ float accT[16 * 129];              //  8256 ring
    __shared__ float accP[64 * 12];               //  3072
    __shared__ float pwb[444];                    //  1776
    // total ~66.4 KB -> 2 blocks/CU (LDS); VGPR cap 128 via launch_bounds(512,2)

    const int tid = threadIdx.x;
    const int wv = tid >> 6, ln = tid & 63;
    const int bid = blockIdx.x;
    const int st  = bid % NSTILE;
    const int grp = (bid / NSTILE) % NGRP;
    const int b   = bid / (NSTILE * NGRP);
    const int bk0 = grp * GBK;
    const int bk1 = (bk0 + GBK < NBK) ? bk0 + GBK : NBK;
    const int T_lo = bk0 * 8 - 2;
    const int s0 = st * 128;
    const bool do_pmt = (st == 0);
    const int ws = (wv & 3) * 32;                 // GEMM1 s-group
    const int wn = (wv >> 2) * 32;                // GEMM1 n-group
    const int sg2 = 16 * wv + (ln & 15);          // GEMM2 s-col

    // ---- B operand in registers (once per block) ----
    short8 bfr[2][8];
    float bssr[2], si2r[2];
#pragma unroll
    for (int nf = 0; nf < 2; ++nf) {
        int scol = s0 + ws + 16 * nf + (ln & 15);
        const bfu* wp = &w4h[(size_t)scol * 256 + (ln >> 4) * 8];
#pragma unroll
        for (int kk = 0; kk < 8; ++kk)
            bfr[nf][kk] = *(const short8*)(const void*)&wp[kk * 32];
        bssr[nf] = (scol < NS) ? bs4[scol] : 0.0f;
        float sc = (scol < NS) ? sis[scol] : 0.0f;
        si2r[nf] = sc * sc;
    }
    if (do_pmt) {
        if (tid < 444)
            pwb[tid] = (tid < 56) ? Wp1[tid] : (tid < 84) ? bp1[tid - 56] :
                       (tid < 420) ? Wp2[tid - 84] : (tid < 432) ? bp2[tid - 420] : psc[tid - 432];
        if (tid < 256) {   // zero rpp rows 12..15 once (never overwritten)
            int p = 12 + (tid >> 6), n = tid & 63;
            rpp[p * 64 + (((n >> 3) ^ (p & 7)) * 8) + (n & 7)] = 0;
        }
    }
    for (int i = tid; i < 16 * 129; i += 512) accT[i] = 0.f;
    for (int i = tid; i < 64 * 12; i += 512) accP[i] = 0.f;
    __syncthreads();

    int F = 0;
    for (int bk = (bk0 > 0 ? bk0 - 1 : 0); bk < bk1; ++bk) {
        const int key = b * NBK + bk;
        const int cnt = counts[key];               // block-uniform
        if (cnt == 0) continue;
        const int off = offs[key];
        const int db8 = (bk - bk0) * 8;

        // flush finalized ring rows [F, db8-2)
        {
            int Fn = db8 - 2; Fn = Fn < 0 ? 0 : Fn;
            if (Fn > F) {
                for (int i = tid; i < (Fn - F) * 128; i += 512) {
                    int dr = i >> 7, s = i & 127;
                    int tl = F + dr;
                    float v = accT[(tl & 15) * 129 + s];
                    accT[(tl & 15) * 129 + s] = 0.f;
                    int tg = T_lo + tl, sg = s0 + s;
                    if (tg >= 0 && tg < NT && sg < NS)
                        outS[((size_t)b * NS + sg) * NT + tg] = v;
                }
                F = Fn;
            }
        }

        const int nch = (cnt + 63) >> 6;
        for (int c = 0; c < nch; ++c) {
            // ---- stage (direct; co-resident block hides latency) ----
            int liN = c * 64 + (tid & 63);
            int giN = off + liN; giN = giN > 32767 ? 32767 : giN;
            int eN = idxl[giN];
            float zN = el[eN * 3 + 2];
            float wN = (liN < cnt) ? wt[eN] : 0.0f;

            {   // s3 rows: 8 threads per row, 4 granules each (named regs, static)
                int rowS = tid >> 3;
                int giS = off + c * 64 + rowS; giS = giS > 32767 ? 32767 : giS;
                int eS = idxl[giS];
                const bfu* srow = s3h + (size_t)eS * 256;
                short8 rg0 = *(const short8*)(const void*)&srow[((tid & 7) * 4 + 0) * 8];
                short8 rg1 = *(const short8*)(const void*)&srow[((tid & 7) * 4 + 1) * 8];
                short8 rg2 = *(const short8*)(const void*)&srow[((tid & 7) * 4 + 2) * 8];
                short8 rg3 = *(const short8*)(const void*)&srow[((tid & 7) * 4 + 3) * 8];
                int r3 = rowS & 7;
                bfu* drow = s3t + rowS * 256;
                *(short8*)(void*)&drow[((((tid & 7) * 4 + 0) ^ r3) * 8)] = rg0;
                *(short8*)(void*)&drow[((((tid & 7) * 4 + 1) ^ r3) * 8)] = rg1;
                *(short8*)(void*)&drow[((((tid & 7) * 4 + 2) ^ r3) * 8)] = rg2;
                *(short8*)(void*)&drow[((((tid & 7) * 4 + 3) ^ r3) * 8)] = rg3;
            }
            {   // gaussian tile Et[16][64]
                int n = tid & 63;
#pragma unroll
                for (int q = 0; q < 2; ++q) {
                    int j = (tid >> 6) * 2 + q;
                    int tg = bk * 8 - 4 + j;
                    int tl = tg - T_lo;
                    float d = (float)tg + 0.5f - zN;
                    bool ok = (tg >= 0) && (tg < NT) && (tl >= 0) && (tl < 64);
                    float g = ok ? wN * GNRM * __expf(-10.0f * d * d) : 0.0f;
                    Et[j * 64 + (((n >> 3) ^ (j & 7)) * 8) + (n & 7)] = f2bf(g);
                }
            }
            if (do_pmt && wv < 6) {                // pmt MLP, waves 0-5, 2 p's each
                float xx = el[eN * 3], yy = el[eN * 3 + 1];
                float hh[28];
#pragma unroll
                for (int j = 0; j < 28; ++j)
                    hh[j] = sigm(xx * pwb[j] + yy * pwb[28 + j] + pwb[56 + j]);
#pragma unroll
                for (int q = 0; q < 2; ++q) {
                    int p = wv * 2 + q;
                    float a = pwb[420 + p];
#pragma unroll
                    for (int j = 0; j < 28; ++j) a += hh[j] * pwb[84 + j * 12 + p];
                    float sc = pwb[432 + p];
                    int n = ln;
                    rpp[p * 64 + (((n >> 3) ^ (p & 7)) * 8) + (n & 7)] = f2bf(sigm(a) * sc * sc);
                }
            }
            __syncthreads();                       // bar1: stage visible

            // ---- GEMM1: (64n x 256k) @ (256k x 128s), wave tile 32n x 32s ----
            f32x4 acc00 = (f32x4){0.f,0.f,0.f,0.f};
            f32x4 acc01 = (f32x4){0.f,0.f,0.f,0.f};
            f32x4 acc10 = (f32x4){0.f,0.f,0.f,0.f};
            f32x4 acc11 = (f32x4){0.f,0.f,0.f,0.f};
            const int ar0 = wn + (ln & 15), ar1 = wn + 16 + (ln & 15);
#pragma unroll
            for (int kk = 0; kk < 8; ++kk) {
                int kc = kk * 4 + (ln >> 4);
                short8 a0 = *(const short8*)(const void*)&s3t[ar0 * 256 + ((kc ^ (ar0 & 7)) * 8)];
                short8 a1 = *(const short8*)(const void*)&s3t[ar1 * 256 + ((kc ^ (ar1 & 7)) * 8)];
                acc00 = __builtin_amdgcn_mfma_f32_16x16x32_bf16(a0, bfr[0][kk], acc00, 0, 0, 0);
                acc01 = __builtin_amdgcn_mfma_f32_16x16x32_bf16(a0, bfr[1][kk], acc01, 0, 0, 0);
                acc10 = __builtin_amdgcn_mfma_f32_16x16x32_bf16(a1, bfr[0][kk], acc10, 0, 0, 0);
                acc11 = __builtin_amdgcn_mfma_f32_16x16x32_bf16(a1, bfr[1][kk], acc11, 0, 0, 0);
            }
            {   // epilogue, fully static
                int sc0 = ws + (ln & 15);
                int sc1 = ws + 16 + (ln & 15);
                int n0a = wn + (ln >> 4) * 4;
                int n0b = wn + 16 + (ln >> 4) * 4;
                short4v pk;
#pragma unroll
                for (int r = 0; r < 4; ++r) pk[r] = (short)f2bf(si2r[0] * sigm(acc00[r] + bssr[0]));
                *(short4v*)(void*)&rpt[sc0 * 64 + (((n0a >> 3) ^ (sc0 & 7)) * 8) + (n0a & 7)] = pk;
#pragma unroll
                for (int r = 0; r < 4; ++r) pk[r] = (short)f2bf(si2r[1] * sigm(acc01[r] + bssr[1]));
                *(short4v*)(void*)&rpt[sc1 * 64 + (((n0a >> 3) ^ (sc1 & 7)) * 8) + (n0a & 7)] = pk;
#pragma unroll
                for (int r = 0; r < 4; ++r) pk[r] = (short)f2bf(si2r[0] * sigm(acc10[r] + bssr[0]));
                *(short4v*)(void*)&rpt[sc0 * 64 + (((n0b >> 3) ^ (sc0 & 7)) * 8) + (n0b & 7)] = pk;
#pragma unroll
                for (int r = 0; r < 4; ++r) pk[r] = (short)f2bf(si2r[1] * sigm(acc11[r] + bssr[1]));
                *(short4v*)(void*)&rpt[sc1 * 64 + (((n0b >> 3) ^ (sc1 & 7)) * 8) + (n0b & 7)] = pk;
            }
            __syncthreads();                       // bar2: rpt visible

            // ---- GEMM2: Et(16t x 64n) @ rpt(64n x 128s) -> ring ----
            {
                f32x4 a2 = (f32x4){0.f,0.f,0.f,0.f};
                f32x4 a2p = (f32x4){0.f,0.f,0.f,0.f};
                const int tr = ln & 15;
#pragma unroll
                for (int kk = 0; kk < 2; ++kk) {
                    int kc = kk * 4 + (ln >> 4);
                    short8 ea = *(const short8*)(const void*)&Et[tr * 64 + ((kc ^ (tr & 7)) * 8)];
                    short8 bb = *(const short8*)(const void*)&rpt[sg2 * 64 + ((kc ^ (sg2 & 7)) * 8)];
                    a2 = __builtin_amdgcn_mfma_f32_16x16x32_bf16(ea, bb, a2, 0, 0, 0);
                    if (do_pmt && wv == 0) {
                        short8 bp = *(const short8*)(const void*)&rpp[tr * 64 + ((kc ^ (tr & 7)) * 8)];
                        a2p = __builtin_amdgcn_mfma_f32_16x16x32_bf16(ea, bp, a2p, 0, 0, 0);
                    }
                }
#pragma unroll
                for (int r = 0; r < 4; ++r) {
                    int tl = db8 - 2 + (ln >> 4) * 4 + r;
                    if (tl >= 0 && tl < 64) accT[(tl & 15) * 129 + sg2] += a2[r];
                }
                if (do_pmt && wv == 0) {
                    int p = ln & 15;
                    if (p < 12) {
#pragma unroll
                        for (int r = 0; r < 4; ++r) {
                            int tl = db8 - 2 + (ln >> 4) * 4 + r;
                            if (tl >= 0 && tl < 64) accP[tl * 12 + p] += a2p[r];
                        }
                    }
                }
            }
            __syncthreads();                       // bar3: GEMM2 reads done
        } // chunks
    } // buckets

    // final flush [F,64)
    for (int i = tid; i < (64 - F) * 128; i += 512) {
        int dr = i >> 7, s = i & 127;
        int tl = F + dr;
        int tg = T_lo + tl, sg = s0 + s;
        if (tg >= 0 && tg < NT && sg < NS)
            outS[((size_t)b * NS + sg) * NT + tg] = accT[(tl & 15) * 129 + s];
    }
    if (do_pmt) {
        for (int i = tid; i < 64 * 12; i += 512) {
            int tl = i / 12, p = i % 12;
            int tg = T_lo + tl;
            if (tg >= 0 && tg < NT)
                outP[((size_t)b * NP + p) * NT + tg] = accP[tl * 12 + p];
        }
    }
}

extern "C" void kernel_launch(void* const* d_in, const int* in_sizes, int n_in,
                              void* d_out, int out_size, void* d_ws, size_t ws_size,
                              hipStream_t stream) {
    const float* el  = (const float*)d_in[0];
    const float* wt  = (const float*)d_in[1];
    const float* Wp1 = (const float*)d_in[2];
    const float* bp1 = (const float*)d_in[3];
    const float* Wp2 = (const float*)d_in[4];
    const float* bp2 = (const float*)d_in[5];
    const float* psc = (const float*)d_in[6];
    const float* Ws1 = (const float*)d_in[7];
    const float* bs1 = (const float*)d_in[8];
    const float* Ws2 = (const float*)d_in[9];
    const float* bs2 = (const float*)d_in[10];
    const float* Ws3 = (const float*)d_in[11];
    const float* bs3 = (const float*)d_in[12];
    const float* Ws4 = (const float*)d_in[13];
    const float* bs4 = (const float*)d_in[14];
    const float* sis = (const float*)d_in[15];
    float* out = (float*)d_out;

    // workspace layout byte-identical to R2/R4..R8 (proven within ws_size)
    char* ws = (char*)d_ws;
    bfu* w2h     = (bfu*)(ws);                    // 16384
    bfu* w3h     = (bfu*)(ws + 16384);            // 65536
    bfu* w4h     = (bfu*)(ws + 81920);            // 1179648
    bfu* s3h     = (bfu*)(ws + 1261568);          // 16777216
    int* counts  = (int*)(ws + 18038784);
    int* offs    = (int*)(ws + 18042880);
    int* cursors = (int*)(ws + 18046976);
    int* idxl    = (int*)(ws + 18051072);         // 131072 -> end 18182144

    hipMemsetAsync(counts, 0, 4096, stream);
    hipMemsetAsync(cursors, 0, 4096, stream);
    // d_out fully written by k_sipm exact-partition stores (proven R6/R7/R8)

    k_prep<<<2464, 256, 0, stream>>>(Ws2, Ws3, Ws4, w2h, w3h, w4h);
    k_count<<<128, 256, 0, stream>>>(el, counts);
    k_scan<<<1, 512, 0, stream>>>(counts, offs);
    k_scatter<<<128, 256, 0, stream>>>(el, offs, cursors, idxl);
    k_mlp<<<256, 256, 0, stream>>>(el, Ws1, bs1, bs2, bs3, w2h, w3h, s3h);
    k_sipm<<<4 * NGRP * NSTILE, 512, 0, stream>>>(el, wt, bs4, sis, Wp1, bp1, Wp2, bp2, psc,
                                                  s3h, w4h, idxl, counts, offs,
                                                  out, out + 4 * NP * NT);
}